// Round 1
// baseline (329.591 us; speedup 1.0000x reference)
//
#include <hip/hip_runtime.h>
#include <hip/hip_bf16.h>
#include <math.h>

// ---------------------------------------------------------------------------
// JAX threefry2x32 (20 rounds), matches jax._src.prng threefry2x32 lowering.
// ---------------------------------------------------------------------------
__host__ __device__ inline void threefry2x32(unsigned k0, unsigned k1,
                                             unsigned x0, unsigned x1,
                                             unsigned* out0, unsigned* out1) {
  unsigned ks0 = k0, ks1 = k1, ks2 = k0 ^ k1 ^ 0x1BD11BDAu;
  x0 += ks0; x1 += ks1;
#define TF_ROUND(r) { x0 += x1; x1 = (x1 << (r)) | (x1 >> (32 - (r))); x1 ^= x0; }
  TF_ROUND(13) TF_ROUND(15) TF_ROUND(26) TF_ROUND(6)
  x0 += ks1; x1 += ks2 + 1u;
  TF_ROUND(17) TF_ROUND(29) TF_ROUND(16) TF_ROUND(24)
  x0 += ks2; x1 += ks0 + 2u;
  TF_ROUND(13) TF_ROUND(15) TF_ROUND(26) TF_ROUND(6)
  x0 += ks0; x1 += ks1 + 3u;
  TF_ROUND(17) TF_ROUND(29) TF_ROUND(16) TF_ROUND(24)
  x0 += ks1; x1 += ks2 + 4u;
  TF_ROUND(13) TF_ROUND(15) TF_ROUND(26) TF_ROUND(6)
  x0 += ks2; x1 += ks0 + 5u;
#undef TF_ROUND
  *out0 = x0; *out1 = x1;
}

// partitionable random_bits for 32-bit: bits = o0 ^ o1 with ctr=(hi,lo)=(0,i)
__device__ inline float jax_uniform01(unsigned key0, unsigned key1, unsigned i) {
  unsigned o0, o1;
  threefry2x32(key0, key1, 0u, i, &o0, &o1);
  unsigned bits = o0 ^ o1;
  return __uint_as_float((bits >> 9) | 0x3f800000u) - 1.0f;
}

// ---------------------------------------------------------------------------
// Graph prep kernels
// ---------------------------------------------------------------------------
__global__ void k_zero(int* p, int n) {
  int i = blockIdx.x * blockDim.x + threadIdx.x;
  if (i < n) p[i] = 0;
}

__global__ void k_deg(const int* __restrict__ ei, int E, int* __restrict__ deg) {
  int e = blockIdx.x * blockDim.x + threadIdx.x;
  if (e >= E) return;
  int d = ei[E + e];  // dst row
  atomicAdd(&deg[d], 1);
}

__global__ void k_scan(const int* __restrict__ deg, int* __restrict__ off, int n) {
  __shared__ int sums[1024];
  int t = threadIdx.x;
  int per = (n + 1023) >> 10;
  int base = t * per;
  int s = 0;
  for (int j = 0; j < per; ++j) { int idx = base + j; if (idx < n) s += deg[idx]; }
  sums[t] = s;
  __syncthreads();
  for (int d = 1; d < 1024; d <<= 1) {
    int v = (t >= d) ? sums[t - d] : 0;
    __syncthreads();
    sums[t] += v;
    __syncthreads();
  }
  int prefix = (t == 0) ? 0 : sums[t - 1];
  for (int j = 0; j < per; ++j) {
    int idx = base + j;
    if (idx < n) { off[idx] = prefix; prefix += deg[idx]; }
  }
  if (t == 1023) off[n] = sums[1023];
}

__global__ void k_prep(const int* __restrict__ deg, const int* __restrict__ off,
                       int* __restrict__ cur, float* __restrict__ dinv, int n) {
  int i = blockIdx.x * blockDim.x + threadIdx.x;
  if (i >= n) return;
  cur[i] = off[i];
  dinv[i] = 1.0f / sqrtf((float)(deg[i] + 1));  // +1: self-loop
}

__global__ void k_fill(const int* __restrict__ ei, int E,
                       int* __restrict__ cur, int* __restrict__ srcs) {
  int e = blockIdx.x * blockDim.x + threadIdx.x;
  if (e >= E) return;
  int s = ei[e];
  int d = ei[E + e];
  int pos = atomicAdd(&cur[d], 1);
  srcs[pos] = s;
}

// ---------------------------------------------------------------------------
// fp32 tiled GEMM: C[M,N] = A[M,K] @ B[K,N].  K % 16 == 0 assumed.
// 64x64 tile, 256 threads, 4x4 micro-tile per thread.
// ---------------------------------------------------------------------------
__global__ __launch_bounds__(256) void k_gemm(const float* __restrict__ A,
                                              const float* __restrict__ B,
                                              float* __restrict__ C,
                                              int M, int N, int K) {
  __shared__ float As[64][17];
  __shared__ float Bs[16][64];
  const int tid = threadIdx.x;
  const int tx = tid & 15, ty = tid >> 4;
  const int row0 = blockIdx.y * 64, col0 = blockIdx.x * 64;
  const int am = tid >> 2;
  const int aq = (tid & 3) * 4;
  const int bk = tid >> 4;
  const int bg = (tid & 15) * 4;
  const bool nvec = ((N & 3) == 0);
  float acc[4][4] = {{0.f}};

  for (int k0 = 0; k0 < K; k0 += 16) {
    // stage A (64 x 16), float4 along K
    {
      int row = row0 + am;
      if (row < M) {
        const float4 v = *reinterpret_cast<const float4*>(&A[(size_t)row * K + k0 + aq]);
        As[am][aq + 0] = v.x; As[am][aq + 1] = v.y;
        As[am][aq + 2] = v.z; As[am][aq + 3] = v.w;
      } else {
        As[am][aq + 0] = 0.f; As[am][aq + 1] = 0.f;
        As[am][aq + 2] = 0.f; As[am][aq + 3] = 0.f;
      }
    }
    // stage B (16 x 64)
    {
      int krow = k0 + bk;
      if (nvec && (col0 + bg + 4 <= N)) {
        const float4 v = *reinterpret_cast<const float4*>(&B[(size_t)krow * N + col0 + bg]);
        Bs[bk][bg + 0] = v.x; Bs[bk][bg + 1] = v.y;
        Bs[bk][bg + 2] = v.z; Bs[bk][bg + 3] = v.w;
      } else {
        for (int j = 0; j < 4; ++j) {
          int col = col0 + bg + j;
          Bs[bk][bg + j] = (col < N) ? B[(size_t)krow * N + col] : 0.f;
        }
      }
    }
    __syncthreads();
#pragma unroll
    for (int kk = 0; kk < 16; ++kk) {
      float a0 = As[ty * 4 + 0][kk];
      float a1 = As[ty * 4 + 1][kk];
      float a2 = As[ty * 4 + 2][kk];
      float a3 = As[ty * 4 + 3][kk];
      float4 bv = *reinterpret_cast<const float4*>(&Bs[kk][tx * 4]);
      acc[0][0] += a0 * bv.x; acc[0][1] += a0 * bv.y; acc[0][2] += a0 * bv.z; acc[0][3] += a0 * bv.w;
      acc[1][0] += a1 * bv.x; acc[1][1] += a1 * bv.y; acc[1][2] += a1 * bv.z; acc[1][3] += a1 * bv.w;
      acc[2][0] += a2 * bv.x; acc[2][1] += a2 * bv.y; acc[2][2] += a2 * bv.z; acc[2][3] += a2 * bv.w;
      acc[3][0] += a3 * bv.x; acc[3][1] += a3 * bv.y; acc[3][2] += a3 * bv.z; acc[3][3] += a3 * bv.w;
    }
    __syncthreads();
  }

  for (int i = 0; i < 4; ++i) {
    int row = row0 + ty * 4 + i;
    if (row >= M) continue;
    for (int j = 0; j < 4; ++j) {
      int col = col0 + tx * 4 + j;
      if (col < N) C[(size_t)row * N + col] = acc[i][j];
    }
  }
}

// ---------------------------------------------------------------------------
// GCN aggregation (+bias, relu, jax-exact dropout).  blockDim.x == feature dim.
// ---------------------------------------------------------------------------
__global__ void k_agg_drop(const float* __restrict__ h, float* __restrict__ out,
                           const int* __restrict__ off, const int* __restrict__ srcs,
                           const float* __restrict__ dinv, const float* __restrict__ bias,
                           unsigned key0, unsigned key1) {
  const int d = blockIdx.x;
  const int F = blockDim.x;
  const int t = threadIdx.x;
  const float dv = dinv[d];
  float acc = h[(size_t)d * F + t] * dv * dv;  // self-loop
  const int e0 = off[d], e1 = off[d + 1];
  for (int e = e0; e < e1; ++e) {
    const int s = srcs[e];
    acc += h[(size_t)s * F + t] * (dinv[s] * dv);
  }
  acc += bias[t];
  acc = fmaxf(acc, 0.0f);                       // relu
  unsigned i = (unsigned)(d * F + t);           // flat index, row-major
  float u = jax_uniform01(key0, key1, i);
  acc = (u < 0.8f) ? (acc / 0.8f) : 0.0f;       // dropout p=0.2
  out[(size_t)d * F + t] = acc;
}

// layer 3: aggregate 10-dim + bias + log_softmax, one thread per node
__global__ void k_agg3_lsm(const float* __restrict__ h, float* __restrict__ out,
                           const int* __restrict__ off, const int* __restrict__ srcs,
                           const float* __restrict__ dinv, const float* __restrict__ b,
                           int n) {
  int d = blockIdx.x * blockDim.x + threadIdx.x;
  if (d >= n) return;
  float acc[10];
  float dv = dinv[d];
#pragma unroll
  for (int f = 0; f < 10; ++f) acc[f] = h[(size_t)d * 10 + f] * dv * dv;
  int e1 = off[d + 1];
  for (int e = off[d]; e < e1; ++e) {
    int s = srcs[e];
    float w = dinv[s] * dv;
#pragma unroll
    for (int f = 0; f < 10; ++f) acc[f] += h[(size_t)s * 10 + f] * w;
  }
  float m = -1e30f;
#pragma unroll
  for (int f = 0; f < 10; ++f) { acc[f] += b[f]; m = fmaxf(m, acc[f]); }
  float sum = 0.f;
#pragma unroll
  for (int f = 0; f < 10; ++f) sum += expf(acc[f] - m);
  float lse = m + logf(sum);
#pragma unroll
  for (int f = 0; f < 10; ++f) out[(size_t)d * 10 + f] = acc[f] - lse;
}

// ---------------------------------------------------------------------------
extern "C" void kernel_launch(void* const* d_in, const int* in_sizes, int n_in,
                              void* d_out, int out_size, void* d_ws, size_t ws_size,
                              hipStream_t stream) {
  const float* x  = (const float*)d_in[0];
  const int*   ei = (const int*)d_in[1];   // [2, E] int32 (harness normalizes ints)
  const float* W1 = (const float*)d_in[2];
  const float* b1 = (const float*)d_in[3];
  const float* W2 = (const float*)d_in[4];
  const float* b2 = (const float*)d_in[5];
  const float* W3 = (const float*)d_in[6];
  const float* b3 = (const float*)d_in[7];
  float* out = (float*)d_out;

  const int N = 20000;
  const int E = in_sizes[1] / 2;
  const int D0 = 512, D1 = 256, D2 = 128, D3 = 10;

  // workspace carve-up
  char* ws = (char*)d_ws;
  auto carve = [&](size_t bytes) -> char* {
    char* p = ws;
    ws += (bytes + 255) & ~(size_t)255;
    return p;
  };
  int*   deg  = (int*)carve((size_t)N * 4);
  int*   off  = (int*)carve((size_t)(N + 1) * 4);
  int*   cur  = (int*)carve((size_t)N * 4);
  float* dinv = (float*)carve((size_t)N * 4);
  int*   srcs = (int*)carve((size_t)E * 4);
  float* bufH = (float*)carve((size_t)N * D1 * 4);
  float* bufA = (float*)carve((size_t)N * D1 * 4);

  // jax.random.key(1) -> (0,1); partitionable fold-like split:
  // dk_j = threefry2x32(key, (0, j))
  unsigned dk1_0, dk1_1, dk2_0, dk2_1;
  threefry2x32(0u, 1u, 0u, 0u, &dk1_0, &dk1_1);
  threefry2x32(0u, 1u, 0u, 1u, &dk2_0, &dk2_1);

  // graph prep (per launch; deterministic up to fp-sum order)
  k_zero<<<(N + 255) / 256, 256, 0, stream>>>(deg, N);
  k_deg<<<(E + 255) / 256, 256, 0, stream>>>(ei, E, deg);
  k_scan<<<1, 1024, 0, stream>>>(deg, off, N);
  k_prep<<<(N + 255) / 256, 256, 0, stream>>>(deg, off, cur, dinv, N);
  k_fill<<<(E + 255) / 256, 256, 0, stream>>>(ei, E, cur, srcs);

  // layer 1: h = x @ W1 ; agg + b1 + relu + dropout(dk1)
  k_gemm<<<dim3((D1 + 63) / 64, (N + 63) / 64), 256, 0, stream>>>(x, W1, bufH, N, D1, D0);
  k_agg_drop<<<N, D1, 0, stream>>>(bufH, bufA, off, srcs, dinv, b1, dk1_0, dk1_1);

  // layer 2
  k_gemm<<<dim3((D2 + 63) / 64, (N + 63) / 64), 256, 0, stream>>>(bufA, W2, bufH, N, D2, D1);
  k_agg_drop<<<N, D2, 0, stream>>>(bufH, bufA, off, srcs, dinv, b2, dk2_0, dk2_1);

  // layer 3 + log_softmax
  k_gemm<<<dim3(1, (N + 63) / 64), 256, 0, stream>>>(bufA, W3, bufH, N, D3, D2);
  k_agg3_lsm<<<(N + 127) / 128, 128, 0, stream>>>(bufH, out, off, srcs, dinv, b3, N);
}

// Round 2
// 226.636 us; speedup vs baseline: 1.4543x; 1.4543x over previous
//
#include <hip/hip_runtime.h>
#include <hip/hip_bf16.h>
#include <math.h>

typedef __attribute__((ext_vector_type(8))) short short8;
typedef __attribute__((ext_vector_type(8))) unsigned short ushort8;
typedef __attribute__((ext_vector_type(4))) float f32x4;

// ---------------------------------------------------------------------------
// JAX threefry2x32 (20 rounds) — verified bit-exact vs jax.random in R1.
// ---------------------------------------------------------------------------
__host__ __device__ inline void threefry2x32(unsigned k0, unsigned k1,
                                             unsigned x0, unsigned x1,
                                             unsigned* out0, unsigned* out1) {
  unsigned ks0 = k0, ks1 = k1, ks2 = k0 ^ k1 ^ 0x1BD11BDAu;
  x0 += ks0; x1 += ks1;
#define TF_ROUND(r) { x0 += x1; x1 = (x1 << (r)) | (x1 >> (32 - (r))); x1 ^= x0; }
  TF_ROUND(13) TF_ROUND(15) TF_ROUND(26) TF_ROUND(6)
  x0 += ks1; x1 += ks2 + 1u;
  TF_ROUND(17) TF_ROUND(29) TF_ROUND(16) TF_ROUND(24)
  x0 += ks2; x1 += ks0 + 2u;
  TF_ROUND(13) TF_ROUND(15) TF_ROUND(26) TF_ROUND(6)
  x0 += ks0; x1 += ks1 + 3u;
  TF_ROUND(17) TF_ROUND(29) TF_ROUND(16) TF_ROUND(24)
  x0 += ks1; x1 += ks2 + 4u;
  TF_ROUND(13) TF_ROUND(15) TF_ROUND(26) TF_ROUND(6)
  x0 += ks2; x1 += ks0 + 5u;
#undef TF_ROUND
  *out0 = x0; *out1 = x1;
}

__device__ inline float jax_uniform01(unsigned key0, unsigned key1, unsigned i) {
  unsigned o0, o1;
  threefry2x32(key0, key1, 0u, i, &o0, &o1);
  unsigned bits = o0 ^ o1;
  return __uint_as_float((bits >> 9) | 0x3f800000u) - 1.0f;
}

__device__ inline unsigned short f2bf(float f) {
  unsigned u = __float_as_uint(f);
  u += 0x7fffu + ((u >> 16) & 1u);   // round-to-nearest-even
  return (unsigned short)(u >> 16);
}

// ---------------------------------------------------------------------------
// Graph prep kernels (unchanged from R1 — passing)
// ---------------------------------------------------------------------------
__global__ void k_zero(int* p, int n) {
  int i = blockIdx.x * blockDim.x + threadIdx.x;
  if (i < n) p[i] = 0;
}

__global__ void k_deg(const int* __restrict__ ei, int E, int* __restrict__ deg) {
  int e = blockIdx.x * blockDim.x + threadIdx.x;
  if (e >= E) return;
  atomicAdd(&deg[ei[E + e]], 1);
}

__global__ void k_scan(const int* __restrict__ deg, int* __restrict__ off, int n) {
  __shared__ int sums[1024];
  int t = threadIdx.x;
  int per = (n + 1023) >> 10;
  int base = t * per;
  int s = 0;
  for (int j = 0; j < per; ++j) { int idx = base + j; if (idx < n) s += deg[idx]; }
  sums[t] = s;
  __syncthreads();
  for (int d = 1; d < 1024; d <<= 1) {
    int v = (t >= d) ? sums[t - d] : 0;
    __syncthreads();
    sums[t] += v;
    __syncthreads();
  }
  int prefix = (t == 0) ? 0 : sums[t - 1];
  for (int j = 0; j < per; ++j) {
    int idx = base + j;
    if (idx < n) { off[idx] = prefix; prefix += deg[idx]; }
  }
  if (t == 1023) off[n] = sums[1023];
}

__global__ void k_prep(const int* __restrict__ deg, const int* __restrict__ off,
                       int* __restrict__ cur, float* __restrict__ dinv, int n) {
  int i = blockIdx.x * blockDim.x + threadIdx.x;
  if (i >= n) return;
  cur[i] = off[i];
  dinv[i] = 1.0f / sqrtf((float)(deg[i] + 1));
}

__global__ void k_fill(const int* __restrict__ ei, int E,
                       int* __restrict__ cur, int* __restrict__ srcs) {
  int e = blockIdx.x * blockDim.x + threadIdx.x;
  if (e >= E) return;
  int s = ei[e];
  int d = ei[E + e];
  int pos = atomicAdd(&cur[d], 1);
  srcs[pos] = s;
}

// W [K,N] fp32 -> WT [N,K] bf16
__global__ void k_cvt_wT(const float* __restrict__ W, unsigned short* __restrict__ WT,
                         int K, int N) {
  int idx = blockIdx.x * blockDim.x + threadIdx.x;
  if (idx >= K * N) return;
  int k = idx / N, n = idx % N;
  WT[(size_t)n * K + k] = f2bf(W[idx]);
}

// ---------------------------------------------------------------------------
// bf16 MFMA GEMM: C[M,N] = A[M,K] @ B[K,N], B given transposed bf16 [N,K].
// BM=64, BN=128, BK=32; 4 waves, each 32x64 (2x4 frags of 16x16x32).
// A either fp32 (converted in staging) or bf16.
// ---------------------------------------------------------------------------
template <bool AF32>
__global__ __launch_bounds__(256) void k_gemm_mfma(const void* __restrict__ Ap,
                                                   const unsigned short* __restrict__ BT,
                                                   float* __restrict__ C,
                                                   int M, int N, int K) {
  __shared__ unsigned short As[64][40];   // 80B rows: 16B-aligned, 2-way-only conflicts
  __shared__ unsigned short Bs[128][40];
  const int tid = threadIdx.x;
  const int row0 = blockIdx.y * 64;
  const int col0 = blockIdx.x * 128;
  const int w = tid >> 6, lane = tid & 63;
  const int wm = w >> 1, wn = w & 1;
  const int lr = lane & 15, lk = lane >> 4;

  f32x4 acc[2][4];
#pragma unroll
  for (int mi = 0; mi < 2; ++mi)
#pragma unroll
    for (int ni = 0; ni < 4; ++ni) acc[mi][ni] = (f32x4)0.0f;

  const int ar = tid >> 2;            // A row 0..63
  const int aseg = (tid & 3) * 8;     // k offset within BK

  for (int k0 = 0; k0 < K; k0 += 32) {
    // ---- stage A (64 x 32 bf16) ----
    {
      int grow = row0 + ar;
      ushort8 av = (ushort8)0;
      if (grow < M) {
        if (AF32) {
          const float* A = (const float*)Ap;
          const float* p = &A[(size_t)grow * K + k0 + aseg];
          float4 v0 = *(const float4*)p;
          float4 v1 = *(const float4*)(p + 4);
          av[0] = f2bf(v0.x); av[1] = f2bf(v0.y); av[2] = f2bf(v0.z); av[3] = f2bf(v0.w);
          av[4] = f2bf(v1.x); av[5] = f2bf(v1.y); av[6] = f2bf(v1.z); av[7] = f2bf(v1.w);
        } else {
          const unsigned short* A = (const unsigned short*)Ap;
          av = *(const ushort8*)&A[(size_t)grow * K + k0 + aseg];
        }
      }
      *(ushort8*)&As[ar][aseg] = av;
    }
    // ---- stage B (128 rows of BT x 32) ----
#pragma unroll
    for (int p = 0; p < 2; ++p) {
      int u = tid + p * 256;
      int br = u >> 2;
      int bseg = (u & 3) * 8;
      ushort8 bv = *(const ushort8*)&BT[(size_t)(col0 + br) * K + k0 + bseg];
      *(ushort8*)&Bs[br][bseg] = bv;
    }
    __syncthreads();

    short8 a[2], b[4];
#pragma unroll
    for (int mi = 0; mi < 2; ++mi)
      a[mi] = *(const short8*)&As[wm * 32 + mi * 16 + lr][lk * 8];
#pragma unroll
    for (int ni = 0; ni < 4; ++ni)
      b[ni] = *(const short8*)&Bs[wn * 64 + ni * 16 + lr][lk * 8];
#pragma unroll
    for (int mi = 0; mi < 2; ++mi)
#pragma unroll
      for (int ni = 0; ni < 4; ++ni)
        acc[mi][ni] = __builtin_amdgcn_mfma_f32_16x16x32_bf16(a[mi], b[ni], acc[mi][ni], 0, 0, 0);
    __syncthreads();
  }

  // epilogue: C/D layout col=lane&15, row=(lane>>4)*4+reg  [m89-verified]
#pragma unroll
  for (int mi = 0; mi < 2; ++mi) {
    int rbase = row0 + wm * 32 + mi * 16 + lk * 4;
#pragma unroll
    for (int j = 0; j < 4; ++j) {
      int row = rbase + j;
      if (row < M) {
#pragma unroll
        for (int ni = 0; ni < 4; ++ni) {
          int col = col0 + wn * 64 + ni * 16 + lr;
          C[(size_t)row * N + col] = acc[mi][ni][j];
        }
      }
    }
  }
}

// ---------------------------------------------------------------------------
// fp32 tiled GEMM (layer 3 only, N=10) — unchanged from R1
// ---------------------------------------------------------------------------
__global__ __launch_bounds__(256) void k_gemm(const float* __restrict__ A,
                                              const float* __restrict__ B,
                                              float* __restrict__ C,
                                              int M, int N, int K) {
  __shared__ float As[64][17];
  __shared__ float Bs[16][64];
  const int tid = threadIdx.x;
  const int tx = tid & 15, ty = tid >> 4;
  const int row0 = blockIdx.y * 64, col0 = blockIdx.x * 64;
  const int am = tid >> 2;
  const int aq = (tid & 3) * 4;
  const int bk = tid >> 4;
  const int bg = (tid & 15) * 4;
  const bool nvec = ((N & 3) == 0);
  float acc[4][4] = {{0.f}};

  for (int k0 = 0; k0 < K; k0 += 16) {
    {
      int row = row0 + am;
      if (row < M) {
        const float4 v = *reinterpret_cast<const float4*>(&A[(size_t)row * K + k0 + aq]);
        As[am][aq + 0] = v.x; As[am][aq + 1] = v.y;
        As[am][aq + 2] = v.z; As[am][aq + 3] = v.w;
      } else {
        As[am][aq + 0] = 0.f; As[am][aq + 1] = 0.f;
        As[am][aq + 2] = 0.f; As[am][aq + 3] = 0.f;
      }
    }
    {
      int krow = k0 + bk;
      if (nvec && (col0 + bg + 4 <= N)) {
        const float4 v = *reinterpret_cast<const float4*>(&B[(size_t)krow * N + col0 + bg]);
        Bs[bk][bg + 0] = v.x; Bs[bk][bg + 1] = v.y;
        Bs[bk][bg + 2] = v.z; Bs[bk][bg + 3] = v.w;
      } else {
        for (int j = 0; j < 4; ++j) {
          int col = col0 + bg + j;
          Bs[bk][bg + j] = (col < N) ? B[(size_t)krow * N + col] : 0.f;
        }
      }
    }
    __syncthreads();
#pragma unroll
    for (int kk = 0; kk < 16; ++kk) {
      float a0 = As[ty * 4 + 0][kk];
      float a1 = As[ty * 4 + 1][kk];
      float a2 = As[ty * 4 + 2][kk];
      float a3 = As[ty * 4 + 3][kk];
      float4 bv = *reinterpret_cast<const float4*>(&Bs[kk][tx * 4]);
      acc[0][0] += a0 * bv.x; acc[0][1] += a0 * bv.y; acc[0][2] += a0 * bv.z; acc[0][3] += a0 * bv.w;
      acc[1][0] += a1 * bv.x; acc[1][1] += a1 * bv.y; acc[1][2] += a1 * bv.z; acc[1][3] += a1 * bv.w;
      acc[2][0] += a2 * bv.x; acc[2][1] += a2 * bv.y; acc[2][2] += a2 * bv.z; acc[2][3] += a2 * bv.w;
      acc[3][0] += a3 * bv.x; acc[3][1] += a3 * bv.y; acc[3][2] += a3 * bv.z; acc[3][3] += a3 * bv.w;
    }
    __syncthreads();
  }

  for (int i = 0; i < 4; ++i) {
    int row = row0 + ty * 4 + i;
    if (row >= M) continue;
    for (int j = 0; j < 4; ++j) {
      int col = col0 + tx * 4 + j;
      if (col < N) C[(size_t)row * N + col] = acc[i][j];
    }
  }
}

// ---------------------------------------------------------------------------
// Wave-per-node GCN aggregation (+bias, relu, jax dropout).
// C floats per lane (F = 64*C); 4 nodes per 256-thread block.
// ---------------------------------------------------------------------------
template <int C, bool OBF>
__global__ __launch_bounds__(256) void k_agg_v2(const float* __restrict__ h,
                                                void* __restrict__ outv,
                                                const int* __restrict__ off,
                                                const int* __restrict__ srcs,
                                                const float* __restrict__ dinv,
                                                const float* __restrict__ bias,
                                                unsigned key0, unsigned key1, int n) {
  const int node = blockIdx.x * (blockDim.x >> 6) + (threadIdx.x >> 6);
  if (node >= n) return;
  const int lane = threadIdx.x & 63;
  const int F = 64 * C;
  const float dv = dinv[node];

  float acc[C];
  {
    const float* rp = h + (size_t)node * F + lane * C;
    float wv = dv * dv;
#pragma unroll
    for (int j = 0; j < C; ++j) acc[j] = rp[j] * wv;
  }
  const int e1 = off[node + 1];
  for (int e = off[node]; e < e1; ++e) {
    int s = srcs[e];
    float wv = dinv[s] * dv;
    const float* rp = h + (size_t)s * F + lane * C;
#pragma unroll
    for (int j = 0; j < C; ++j) acc[j] += rp[j] * wv;
  }
#pragma unroll
  for (int j = 0; j < C; ++j) {
    float v = acc[j] + bias[lane * C + j];
    v = fmaxf(v, 0.0f);
    unsigned i = (unsigned)(node * F + lane * C + j);
    float u = jax_uniform01(key0, key1, i);
    v = (u < 0.8f) ? (v * 1.25f) : 0.0f;
    acc[j] = v;
  }
  if (OBF) {
    unsigned short* op = (unsigned short*)outv + (size_t)node * F + lane * C;
#pragma unroll
    for (int j = 0; j < C; ++j) op[j] = f2bf(acc[j]);
  } else {
    float* op = (float*)outv + (size_t)node * F + lane * C;
#pragma unroll
    for (int j = 0; j < C; ++j) op[j] = acc[j];
  }
}

// layer 3: aggregate 10-dim + bias + log_softmax, one thread per node
__global__ void k_agg3_lsm(const float* __restrict__ h, float* __restrict__ out,
                           const int* __restrict__ off, const int* __restrict__ srcs,
                           const float* __restrict__ dinv, const float* __restrict__ b,
                           int n) {
  int d = blockIdx.x * blockDim.x + threadIdx.x;
  if (d >= n) return;
  float acc[10];
  float dv = dinv[d];
#pragma unroll
  for (int f = 0; f < 10; ++f) acc[f] = h[(size_t)d * 10 + f] * dv * dv;
  int e1 = off[d + 1];
  for (int e = off[d]; e < e1; ++e) {
    int s = srcs[e];
    float w = dinv[s] * dv;
#pragma unroll
    for (int f = 0; f < 10; ++f) acc[f] += h[(size_t)s * 10 + f] * w;
  }
  float m = -1e30f;
#pragma unroll
  for (int f = 0; f < 10; ++f) { acc[f] += b[f]; m = fmaxf(m, acc[f]); }
  float sum = 0.f;
#pragma unroll
  for (int f = 0; f < 10; ++f) sum += expf(acc[f] - m);
  float lse = m + logf(sum);
#pragma unroll
  for (int f = 0; f < 10; ++f) out[(size_t)d * 10 + f] = acc[f] - lse;
}

// ---------------------------------------------------------------------------
extern "C" void kernel_launch(void* const* d_in, const int* in_sizes, int n_in,
                              void* d_out, int out_size, void* d_ws, size_t ws_size,
                              hipStream_t stream) {
  const float* x  = (const float*)d_in[0];
  const int*   ei = (const int*)d_in[1];
  const float* W1 = (const float*)d_in[2];
  const float* b1 = (const float*)d_in[3];
  const float* W2 = (const float*)d_in[4];
  const float* b2 = (const float*)d_in[5];
  const float* W3 = (const float*)d_in[6];
  const float* b3 = (const float*)d_in[7];
  float* out = (float*)d_out;

  const int N = 20000;
  const int E = in_sizes[1] / 2;
  const int D1 = 256, D2 = 128;

  char* ws = (char*)d_ws;
  auto carve = [&](size_t bytes) -> char* {
    char* p = ws;
    ws += (bytes + 255) & ~(size_t)255;
    return p;
  };
  int*   deg  = (int*)carve((size_t)N * 4);
  int*   off  = (int*)carve((size_t)(N + 1) * 4);
  int*   cur  = (int*)carve((size_t)N * 4);
  float* dinv = (float*)carve((size_t)N * 4);
  int*   srcs = (int*)carve((size_t)E * 4);
  unsigned short* W1T = (unsigned short*)carve((size_t)D1 * 512 * 2);
  unsigned short* W2T = (unsigned short*)carve((size_t)D2 * D1 * 2);
  float* bufH = (float*)carve((size_t)N * D1 * 4);              // h1 / h2 / h3 (reused)
  unsigned short* bufA_bf = (unsigned short*)carve((size_t)N * D1 * 2);  // agg1 out (bf16)
  float* bufA2 = (float*)bufA_bf;                                // agg2 out reuses (GEMM2 done)

  unsigned dk1_0, dk1_1, dk2_0, dk2_1;
  threefry2x32(0u, 1u, 0u, 0u, &dk1_0, &dk1_1);
  threefry2x32(0u, 1u, 0u, 1u, &dk2_0, &dk2_1);

  // graph prep + weight conversion
  k_zero<<<(N + 255) / 256, 256, 0, stream>>>(deg, N);
  k_deg<<<(E + 255) / 256, 256, 0, stream>>>(ei, E, deg);
  k_scan<<<1, 1024, 0, stream>>>(deg, off, N);
  k_prep<<<(N + 255) / 256, 256, 0, stream>>>(deg, off, cur, dinv, N);
  k_fill<<<(E + 255) / 256, 256, 0, stream>>>(ei, E, cur, srcs);
  k_cvt_wT<<<(512 * D1 + 255) / 256, 256, 0, stream>>>(W1, W1T, 512, D1);
  k_cvt_wT<<<(D1 * D2 + 255) / 256, 256, 0, stream>>>(W2, W2T, D1, D2);

  // layer 1: h1 = x @ W1 (bf16 MFMA); agg + b1 + relu + dropout(dk1) -> bf16
  k_gemm_mfma<true><<<dim3(D1 / 128, (N + 63) / 64), 256, 0, stream>>>(x, W1T, bufH, N, D1, 512);
  k_agg_v2<4, true><<<(N + 3) / 4, 256, 0, stream>>>(bufH, bufA_bf, off, srcs, dinv, b1, dk1_0, dk1_1, N);

  // layer 2: h2 = a1 @ W2 (bf16 MFMA); agg + b2 + relu + dropout(dk2) -> fp32
  k_gemm_mfma<false><<<dim3(D2 / 128, (N + 63) / 64), 256, 0, stream>>>(bufA_bf, W2T, bufH, N, D2, D1);
  k_agg_v2<2, false><<<(N + 3) / 4, 256, 0, stream>>>(bufH, bufA2, off, srcs, dinv, b2, dk2_0, dk2_1, N);

  // layer 3 (fp32, N=10) + log_softmax
  k_gemm<<<dim3(1, (N + 63) / 64), 256, 0, stream>>>(bufA2, W3, bufH, N, 10, D2);
  k_agg3_lsm<<<(N + 127) / 128, 128, 0, stream>>>(bufH, out, off, srcs, dinv, b3, N);
}

// Round 3
// 184.951 us; speedup vs baseline: 1.7820x; 1.2254x over previous
//
#include <hip/hip_runtime.h>
#include <hip/hip_bf16.h>
#include <math.h>

typedef __attribute__((ext_vector_type(8))) short short8;
typedef __attribute__((ext_vector_type(8))) unsigned short ushort8;
typedef __attribute__((ext_vector_type(4))) unsigned short ushort4v;
typedef __attribute__((ext_vector_type(2))) unsigned short ushort2v;
typedef __attribute__((ext_vector_type(4))) float f32x4;

// ---------------------------------------------------------------------------
// JAX threefry2x32 (20 rounds) — verified bit-exact vs jax.random in R1.
// ---------------------------------------------------------------------------
__host__ __device__ inline void threefry2x32(unsigned k0, unsigned k1,
                                             unsigned x0, unsigned x1,
                                             unsigned* out0, unsigned* out1) {
  unsigned ks0 = k0, ks1 = k1, ks2 = k0 ^ k1 ^ 0x1BD11BDAu;
  x0 += ks0; x1 += ks1;
#define TF_ROUND(r) { x0 += x1; x1 = (x1 << (r)) | (x1 >> (32 - (r))); x1 ^= x0; }
  TF_ROUND(13) TF_ROUND(15) TF_ROUND(26) TF_ROUND(6)
  x0 += ks1; x1 += ks2 + 1u;
  TF_ROUND(17) TF_ROUND(29) TF_ROUND(16) TF_ROUND(24)
  x0 += ks2; x1 += ks0 + 2u;
  TF_ROUND(13) TF_ROUND(15) TF_ROUND(26) TF_ROUND(6)
  x0 += ks0; x1 += ks1 + 3u;
  TF_ROUND(17) TF_ROUND(29) TF_ROUND(16) TF_ROUND(24)
  x0 += ks1; x1 += ks2 + 4u;
  TF_ROUND(13) TF_ROUND(15) TF_ROUND(26) TF_ROUND(6)
  x0 += ks2; x1 += ks0 + 5u;
#undef TF_ROUND
  *out0 = x0; *out1 = x1;
}

__device__ inline float jax_uniform01(unsigned key0, unsigned key1, unsigned i) {
  unsigned o0, o1;
  threefry2x32(key0, key1, 0u, i, &o0, &o1);
  unsigned bits = o0 ^ o1;
  return __uint_as_float((bits >> 9) | 0x3f800000u) - 1.0f;
}

__device__ inline unsigned short f2bf(float f) {
  unsigned u = __float_as_uint(f);
  u += 0x7fffu + ((u >> 16) & 1u);   // round-to-nearest-even
  return (unsigned short)(u >> 16);
}

__device__ inline float bf2f(unsigned short b) {
  return __uint_as_float(((unsigned)b) << 16);
}

// ---------------------------------------------------------------------------
// Graph prep kernels (unchanged — passing)
// ---------------------------------------------------------------------------
__global__ void k_zero(int* p, int n) {
  int i = blockIdx.x * blockDim.x + threadIdx.x;
  if (i < n) p[i] = 0;
}

__global__ void k_deg(const int* __restrict__ ei, int E, int* __restrict__ deg) {
  int e = blockIdx.x * blockDim.x + threadIdx.x;
  if (e >= E) return;
  atomicAdd(&deg[ei[E + e]], 1);
}

__global__ void k_scan(const int* __restrict__ deg, int* __restrict__ off, int n) {
  __shared__ int sums[1024];
  int t = threadIdx.x;
  int per = (n + 1023) >> 10;
  int base = t * per;
  int s = 0;
  for (int j = 0; j < per; ++j) { int idx = base + j; if (idx < n) s += deg[idx]; }
  sums[t] = s;
  __syncthreads();
  for (int d = 1; d < 1024; d <<= 1) {
    int v = (t >= d) ? sums[t - d] : 0;
    __syncthreads();
    sums[t] += v;
    __syncthreads();
  }
  int prefix = (t == 0) ? 0 : sums[t - 1];
  for (int j = 0; j < per; ++j) {
    int idx = base + j;
    if (idx < n) { off[idx] = prefix; prefix += deg[idx]; }
  }
  if (t == 1023) off[n] = sums[1023];
}

__global__ void k_prep(const int* __restrict__ deg, const int* __restrict__ off,
                       int* __restrict__ cur, float* __restrict__ dinv, int n) {
  int i = blockIdx.x * blockDim.x + threadIdx.x;
  if (i >= n) return;
  cur[i] = off[i];
  dinv[i] = 1.0f / sqrtf((float)(deg[i] + 1));
}

__global__ void k_fill(const int* __restrict__ ei, int E,
                       int* __restrict__ cur, int* __restrict__ srcs) {
  int e = blockIdx.x * blockDim.x + threadIdx.x;
  if (e >= E) return;
  int s = ei[e];
  int d = ei[E + e];
  int pos = atomicAdd(&cur[d], 1);
  srcs[pos] = s;
}

// W [K,N] fp32 -> WT [N,K] bf16
__global__ void k_cvt_wT(const float* __restrict__ W, unsigned short* __restrict__ WT,
                         int K, int N) {
  int idx = blockIdx.x * blockDim.x + threadIdx.x;
  if (idx >= K * N) return;
  int k = idx / N, n = idx % N;
  WT[(size_t)n * K + k] = f2bf(W[idx]);
}

// ---------------------------------------------------------------------------
// bf16 MFMA GEMM: C[M,N] = A[M,K] @ B[K,N], B given transposed bf16 [N,K].
// BM=64, BN=128, BK=32; 4 waves, each 32x64 (2x4 frags of 16x16x32).
// A fp32 (converted in staging) or bf16; C fp32 or bf16.
// ---------------------------------------------------------------------------
template <bool AF32, bool OBF>
__global__ __launch_bounds__(256) void k_gemm_mfma(const void* __restrict__ Ap,
                                                   const unsigned short* __restrict__ BT,
                                                   void* __restrict__ Cp,
                                                   int M, int N, int K) {
  __shared__ unsigned short As[64][40];   // 80B rows: 16B-aligned, 2-way-only conflicts
  __shared__ unsigned short Bs[128][40];
  const int tid = threadIdx.x;
  const int row0 = blockIdx.y * 64;
  const int col0 = blockIdx.x * 128;
  const int w = tid >> 6, lane = tid & 63;
  const int wm = w >> 1, wn = w & 1;
  const int lr = lane & 15, lk = lane >> 4;

  f32x4 acc[2][4];
#pragma unroll
  for (int mi = 0; mi < 2; ++mi)
#pragma unroll
    for (int ni = 0; ni < 4; ++ni) acc[mi][ni] = (f32x4)0.0f;

  const int ar = tid >> 2;            // A row 0..63
  const int aseg = (tid & 3) * 8;     // k offset within BK

  for (int k0 = 0; k0 < K; k0 += 32) {
    // ---- stage A (64 x 32 bf16) ----
    {
      int grow = row0 + ar;
      ushort8 av = (ushort8)0;
      if (grow < M) {
        if (AF32) {
          const float* A = (const float*)Ap;
          const float* p = &A[(size_t)grow * K + k0 + aseg];
          float4 v0 = *(const float4*)p;
          float4 v1 = *(const float4*)(p + 4);
          av[0] = f2bf(v0.x); av[1] = f2bf(v0.y); av[2] = f2bf(v0.z); av[3] = f2bf(v0.w);
          av[4] = f2bf(v1.x); av[5] = f2bf(v1.y); av[6] = f2bf(v1.z); av[7] = f2bf(v1.w);
        } else {
          const unsigned short* A = (const unsigned short*)Ap;
          av = *(const ushort8*)&A[(size_t)grow * K + k0 + aseg];
        }
      }
      *(ushort8*)&As[ar][aseg] = av;
    }
    // ---- stage B (128 rows of BT x 32) ----
#pragma unroll
    for (int p = 0; p < 2; ++p) {
      int u = tid + p * 256;
      int br = u >> 2;
      int bseg = (u & 3) * 8;
      ushort8 bv = *(const ushort8*)&BT[(size_t)(col0 + br) * K + k0 + bseg];
      *(ushort8*)&Bs[br][bseg] = bv;
    }
    __syncthreads();

    short8 a[2], b[4];
#pragma unroll
    for (int mi = 0; mi < 2; ++mi)
      a[mi] = *(const short8*)&As[wm * 32 + mi * 16 + lr][lk * 8];
#pragma unroll
    for (int ni = 0; ni < 4; ++ni)
      b[ni] = *(const short8*)&Bs[wn * 64 + ni * 16 + lr][lk * 8];
#pragma unroll
    for (int mi = 0; mi < 2; ++mi)
#pragma unroll
      for (int ni = 0; ni < 4; ++ni)
        acc[mi][ni] = __builtin_amdgcn_mfma_f32_16x16x32_bf16(a[mi], b[ni], acc[mi][ni], 0, 0, 0);
    __syncthreads();
  }

  // epilogue: C/D layout col=lane&15, row=(lane>>4)*4+reg  [m89-verified]
#pragma unroll
  for (int mi = 0; mi < 2; ++mi) {
    int rbase = row0 + wm * 32 + mi * 16 + lk * 4;
#pragma unroll
    for (int j = 0; j < 4; ++j) {
      int row = rbase + j;
      if (row < M) {
#pragma unroll
        for (int ni = 0; ni < 4; ++ni) {
          int col = col0 + wn * 64 + ni * 16 + lr;
          if (OBF) {
            ((unsigned short*)Cp)[(size_t)row * N + col] = f2bf(acc[mi][ni][j]);
          } else {
            ((float*)Cp)[(size_t)row * N + col] = acc[mi][ni][j];
          }
        }
      }
    }
  }
}

// ---------------------------------------------------------------------------
// fp32 tiled GEMM (layer 3 only, N=10)
// ---------------------------------------------------------------------------
__global__ __launch_bounds__(256) void k_gemm(const float* __restrict__ A,
                                              const float* __restrict__ B,
                                              float* __restrict__ C,
                                              int M, int N, int K) {
  __shared__ float As[64][17];
  __shared__ float Bs[16][64];
  const int tid = threadIdx.x;
  const int tx = tid & 15, ty = tid >> 4;
  const int row0 = blockIdx.y * 64, col0 = blockIdx.x * 64;
  const int am = tid >> 2;
  const int aq = (tid & 3) * 4;
  const int bk = tid >> 4;
  const int bg = (tid & 15) * 4;
  const bool nvec = ((N & 3) == 0);
  float acc[4][4] = {{0.f}};

  for (int k0 = 0; k0 < K; k0 += 16) {
    {
      int row = row0 + am;
      if (row < M) {
        const float4 v = *reinterpret_cast<const float4*>(&A[(size_t)row * K + k0 + aq]);
        As[am][aq + 0] = v.x; As[am][aq + 1] = v.y;
        As[am][aq + 2] = v.z; As[am][aq + 3] = v.w;
      } else {
        As[am][aq + 0] = 0.f; As[am][aq + 1] = 0.f;
        As[am][aq + 2] = 0.f; As[am][aq + 3] = 0.f;
      }
    }
    {
      int krow = k0 + bk;
      if (nvec && (col0 + bg + 4 <= N)) {
        const float4 v = *reinterpret_cast<const float4*>(&B[(size_t)krow * N + col0 + bg]);
        Bs[bk][bg + 0] = v.x; Bs[bk][bg + 1] = v.y;
        Bs[bk][bg + 2] = v.z; Bs[bk][bg + 3] = v.w;
      } else {
        for (int j = 0; j < 4; ++j) {
          int col = col0 + bg + j;
          Bs[bk][bg + j] = (col < N) ? B[(size_t)krow * N + col] : 0.f;
        }
      }
    }
    __syncthreads();
#pragma unroll
    for (int kk = 0; kk < 16; ++kk) {
      float a0 = As[ty * 4 + 0][kk];
      float a1 = As[ty * 4 + 1][kk];
      float a2 = As[ty * 4 + 2][kk];
      float a3 = As[ty * 4 + 3][kk];
      float4 bv = *reinterpret_cast<const float4*>(&Bs[kk][tx * 4]);
      acc[0][0] += a0 * bv.x; acc[0][1] += a0 * bv.y; acc[0][2] += a0 * bv.z; acc[0][3] += a0 * bv.w;
      acc[1][0] += a1 * bv.x; acc[1][1] += a1 * bv.y; acc[1][2] += a1 * bv.z; acc[1][3] += a1 * bv.w;
      acc[2][0] += a2 * bv.x; acc[2][1] += a2 * bv.y; acc[2][2] += a2 * bv.z; acc[2][3] += a2 * bv.w;
      acc[3][0] += a3 * bv.x; acc[3][1] += a3 * bv.y; acc[3][2] += a3 * bv.z; acc[3][3] += a3 * bv.w;
    }
    __syncthreads();
  }

  for (int i = 0; i < 4; ++i) {
    int row = row0 + ty * 4 + i;
    if (row >= M) continue;
    for (int j = 0; j < 4; ++j) {
      int col = col0 + tx * 4 + j;
      if (col < N) C[(size_t)row * N + col] = acc[i][j];
    }
  }
}

// ---------------------------------------------------------------------------
// Wave-per-node GCN aggregation over bf16 h (+bias, relu, jax dropout).
// C bf16 elems per lane (F = 64*C); 4 nodes per 256-thread block.
// Edge loop unrolled x4 for memory-level parallelism.
// ---------------------------------------------------------------------------
template <int C, bool OBF>
__global__ __launch_bounds__(256) void k_agg_bf(const unsigned short* __restrict__ h,
                                                void* __restrict__ outv,
                                                const int* __restrict__ off,
                                                const int* __restrict__ srcs,
                                                const float* __restrict__ dinv,
                                                const float* __restrict__ bias,
                                                unsigned key0, unsigned key1, int n) {
  typedef __attribute__((ext_vector_type(C))) unsigned short ushortC;
  const int node = blockIdx.x * (blockDim.x >> 6) + (threadIdx.x >> 6);
  if (node >= n) return;
  const int lane = threadIdx.x & 63;
  const int F = 64 * C;
  const float dv = dinv[node];

  float acc[C];
  {
    ushortC r = *(const ushortC*)(h + (size_t)node * F + lane * C);
    float wv = dv * dv;
#pragma unroll
    for (int j = 0; j < C; ++j) acc[j] = bf2f(r[j]) * wv;
  }
  int e = off[node];
  const int e1 = off[node + 1];
  for (; e + 4 <= e1; e += 4) {
    int s0 = srcs[e + 0], s1 = srcs[e + 1], s2 = srcs[e + 2], s3 = srcs[e + 3];
    float w0 = dinv[s0] * dv, w1 = dinv[s1] * dv, w2 = dinv[s2] * dv, w3 = dinv[s3] * dv;
    ushortC r0 = *(const ushortC*)(h + (size_t)s0 * F + lane * C);
    ushortC r1 = *(const ushortC*)(h + (size_t)s1 * F + lane * C);
    ushortC r2 = *(const ushortC*)(h + (size_t)s2 * F + lane * C);
    ushortC r3 = *(const ushortC*)(h + (size_t)s3 * F + lane * C);
#pragma unroll
    for (int j = 0; j < C; ++j)
      acc[j] += bf2f(r0[j]) * w0 + bf2f(r1[j]) * w1 + bf2f(r2[j]) * w2 + bf2f(r3[j]) * w3;
  }
  for (; e < e1; ++e) {
    int s = srcs[e];
    float wv = dinv[s] * dv;
    ushortC r = *(const ushortC*)(h + (size_t)s * F + lane * C);
#pragma unroll
    for (int j = 0; j < C; ++j) acc[j] += bf2f(r[j]) * wv;
  }
#pragma unroll
  for (int j = 0; j < C; ++j) {
    float v = acc[j] + bias[lane * C + j];
    v = fmaxf(v, 0.0f);
    unsigned i = (unsigned)(node * F + lane * C + j);
    float u = jax_uniform01(key0, key1, i);
    v = (u < 0.8f) ? (v * 1.25f) : 0.0f;
    acc[j] = v;
  }
  if (OBF) {
    unsigned short* op = (unsigned short*)outv + (size_t)node * F + lane * C;
#pragma unroll
    for (int j = 0; j < C; ++j) op[j] = f2bf(acc[j]);
  } else {
    float* op = (float*)outv + (size_t)node * F + lane * C;
#pragma unroll
    for (int j = 0; j < C; ++j) op[j] = acc[j];
  }
}

// layer 3: aggregate 10-dim + bias + log_softmax, one thread per node
__global__ void k_agg3_lsm(const float* __restrict__ h, float* __restrict__ out,
                           const int* __restrict__ off, const int* __restrict__ srcs,
                           const float* __restrict__ dinv, const float* __restrict__ b,
                           int n) {
  int d = blockIdx.x * blockDim.x + threadIdx.x;
  if (d >= n) return;
  float acc[10];
  float dv = dinv[d];
#pragma unroll
  for (int f = 0; f < 10; ++f) acc[f] = h[(size_t)d * 10 + f] * dv * dv;
  int e1 = off[d + 1];
  for (int e = off[d]; e < e1; ++e) {
    int s = srcs[e];
    float w = dinv[s] * dv;
#pragma unroll
    for (int f = 0; f < 10; ++f) acc[f] += h[(size_t)s * 10 + f] * w;
  }
  float m = -1e30f;
#pragma unroll
  for (int f = 0; f < 10; ++f) { acc[f] += b[f]; m = fmaxf(m, acc[f]); }
  float sum = 0.f;
#pragma unroll
  for (int f = 0; f < 10; ++f) sum += expf(acc[f] - m);
  float lse = m + logf(sum);
#pragma unroll
  for (int f = 0; f < 10; ++f) out[(size_t)d * 10 + f] = acc[f] - lse;
}

// ---------------------------------------------------------------------------
extern "C" void kernel_launch(void* const* d_in, const int* in_sizes, int n_in,
                              void* d_out, int out_size, void* d_ws, size_t ws_size,
                              hipStream_t stream) {
  const float* x  = (const float*)d_in[0];
  const int*   ei = (const int*)d_in[1];
  const float* W1 = (const float*)d_in[2];
  const float* b1 = (const float*)d_in[3];
  const float* W2 = (const float*)d_in[4];
  const float* b2 = (const float*)d_in[5];
  const float* W3 = (const float*)d_in[6];
  const float* b3 = (const float*)d_in[7];
  float* out = (float*)d_out;

  const int N = 20000;
  const int E = in_sizes[1] / 2;
  const int D1 = 256, D2 = 128;

  char* ws = (char*)d_ws;
  auto carve = [&](size_t bytes) -> char* {
    char* p = ws;
    ws += (bytes + 255) & ~(size_t)255;
    return p;
  };
  int*   deg  = (int*)carve((size_t)N * 4);
  int*   off  = (int*)carve((size_t)(N + 1) * 4);
  int*   cur  = (int*)carve((size_t)N * 4);
  float* dinv = (float*)carve((size_t)N * 4);
  int*   srcs = (int*)carve((size_t)E * 4);
  unsigned short* W1T = (unsigned short*)carve((size_t)D1 * 512 * 2);
  unsigned short* W2T = (unsigned short*)carve((size_t)D2 * D1 * 2);
  unsigned short* bufHb = (unsigned short*)carve((size_t)N * D1 * 2); // h1(bf16) then h2(bf16)
  unsigned short* bufA_bf = (unsigned short*)carve((size_t)N * D1 * 2); // agg1 out bf16; later agg2 out fp32
  float* bufA2 = (float*)bufA_bf;   // agg2 fp32 output (N*128*4 == N*256*2 bytes, reuse)
  float* bufH3 = (float*)carve((size_t)N * 10 * 4);  // h3 fp32

  unsigned dk1_0, dk1_1, dk2_0, dk2_1;
  threefry2x32(0u, 1u, 0u, 0u, &dk1_0, &dk1_1);
  threefry2x32(0u, 1u, 0u, 1u, &dk2_0, &dk2_1);

  // graph prep + weight conversion
  k_zero<<<(N + 255) / 256, 256, 0, stream>>>(deg, N);
  k_deg<<<(E + 255) / 256, 256, 0, stream>>>(ei, E, deg);
  k_scan<<<1, 1024, 0, stream>>>(deg, off, N);
  k_prep<<<(N + 255) / 256, 256, 0, stream>>>(deg, off, cur, dinv, N);
  k_fill<<<(E + 255) / 256, 256, 0, stream>>>(ei, E, cur, srcs);
  k_cvt_wT<<<(512 * D1 + 255) / 256, 256, 0, stream>>>(W1, W1T, 512, D1);
  k_cvt_wT<<<(D1 * D2 + 255) / 256, 256, 0, stream>>>(W2, W2T, D1, D2);

  // layer 1: h1(bf16) = x @ W1 ; agg + b1 + relu + dropout(dk1) -> bf16
  k_gemm_mfma<true, true><<<dim3(D1 / 128, (N + 63) / 64), 256, 0, stream>>>(x, W1T, bufHb, N, D1, 512);
  k_agg_bf<4, true><<<(N + 3) / 4, 256, 0, stream>>>(bufHb, bufA_bf, off, srcs, dinv, b1, dk1_0, dk1_1, N);

  // layer 2: h2(bf16) = a1 @ W2 ; agg + b2 + relu + dropout(dk2) -> fp32
  k_gemm_mfma<false, true><<<dim3(D2 / 128, (N + 63) / 64), 256, 0, stream>>>(bufA_bf, W2T, bufHb, N, D2, D1);
  k_agg_bf<2, false><<<(N + 3) / 4, 256, 0, stream>>>(bufHb, bufA2, off, srcs, dinv, b2, dk2_0, dk2_1, N);

  // layer 3 (fp32, N=10) + log_softmax
  k_gemm<<<dim3(1, (N + 63) / 64), 256, 0, stream>>>(bufA2, W3, bufH3, N, 10, D2);
  k_agg3_lsm<<<(N + 127) / 128, 128, 0, stream>>>(bufH3, out, off, srcs, dinv, b3, N);
}